// Round 4
// baseline (505.093 us; speedup 1.0000x reference)
//
#include <hip/hip_runtime.h>
#include <hip/hip_bf16.h>
#include <stdint.h>
#include <math.h>

// ---------------------------------------------------------------------------
// SelfAttention: x[4,2048,1024] fp32, W_qkv[3072,1024], W_out[1024,1024]
// bf16 MFMA everywhere; fp32 accuracy via hi/lo split-bf16 GEMMs.
// R4: GEMM rebuilt as counted-vmcnt ring pipeline (T2+T3+T4+T5):
//     256x128 tile, BK=64, 3-slot LDS ring (144 KB), prefetch distance 2,
//     vmcnt(6) per-tile (never 0 in main loop), XOR-swizzled LDS (2-way free),
//     2 phases/tile with setprio'd 16-MFMA clusters. attn frozen from R3.
// ---------------------------------------------------------------------------

using short8 = __attribute__((ext_vector_type(8))) short;
using f32x4  = __attribute__((ext_vector_type(4))) float;
using f32x16 = __attribute__((ext_vector_type(16))) float;
using u32x4  = __attribute__((ext_vector_type(4))) unsigned int;

#define HID   1024
#define NHEAD 16
#define HDIM  64
#define NB    4
#define SEQ   2048
#define MROWS (NB*SEQ)   // 8192
#define KP    3072       // logical split-K
#define NKT   (KP/64)    // 48 K-tiles of 64

typedef __attribute__((address_space(1))) const void* gas_t;
typedef __attribute__((address_space(3))) void*       las_t;

__device__ __forceinline__ uint16_t f2b(float f){
  uint32_t u = __float_as_uint(f);
  uint32_t r = (u + 0x7FFFu + ((u >> 16) & 1u)) >> 16;   // RNE
  return (uint16_t)r;
}
__device__ __forceinline__ float b2f(uint16_t h){
  return __uint_as_float(((uint32_t)h) << 16);
}

// fp32 [rows][1024] -> bf16 [rows][2048] = [hi | lo]; rows < nscale scaled by qs
__global__ void split_hilo(const float* __restrict__ in, uint16_t* __restrict__ out,
                           int n, int nscale, float qs){
  int i = blockIdx.x * 256 + threadIdx.x;
  if (i >= n) return;
  int r = i >> 10, c = i & 1023;
  float v = in[i];
  if (r < nscale) v *= qs;           // q-scale (incl. log2e for exp2-domain)
  uint16_t hi = f2b(v);
  uint16_t lo = f2b(v - b2f(hi));
  out[(size_t)r*2048 + c]        = hi;
  out[(size_t)r*2048 + 1024 + c] = lo;
}

// ---------------------------------------------------------------------------
// R4 pipelined split-K' GEMM.
// C[m][n] = sum_{k'<3072} A2[m][mapA(k')] * B2[n][mapB(k')]
//   mapA = k'<2048 ? k' : k'-2048   (Ah, Al, Ah)
//   mapB = k'<1024 ? k' : k'-1024   (Bh, Bh, Bl)
// Tile 256x128, BK=64. 8 waves as 4m x 2n, 64x64 per wave.
// LDS ring: 3 slots x (A[256][64] + B[128][64]) bf16, XOR-swizzled
//   byte ^= ((row&7)<<4)  (involution; staged via inverse-swizzled global src).
// Schedule per K-tile t: [vmcnt(6); barrier; stage half0 of t+2; reads+MFMA k0]
//                        [barrier;            stage half1 of t+2; reads+MFMA k1]
// Counting: each wave issues 6 loads/tile in order; vmcnt(6) at tile t top =>
// every wave's tile-t loads landed => cooperative tile complete. vmcnt(0) only
// at the last tile.
// ---------------------------------------------------------------------------
__device__ __forceinline__ void stage_half(const uint16_t* __restrict__ A,
                                           const uint16_t* __restrict__ B,
                                           uint16_t* la, uint16_t* lb,
                                           int m0, int n0, int kt,
                                           int t, int wid, int h){
  int kp = kt*64;
  int ka = (kp < 2048) ? kp : kp - 2048;
  int kb = (kp < 1024) ? kp : kp - 1024;
  // A: rows h*128 .. h*128+128 (1024 16B-slots, 2 per thread)
#pragma unroll
  for (int i = 0; i < 2; ++i){
    int tl = h*1024 + i*512 + t;
    int row = tl >> 3;                       // 128B rows
    int cb  = ((tl & 7)*16) ^ ((row & 7) << 4);
    __builtin_amdgcn_global_load_lds(
        (gas_t)((const char*)(A + (size_t)(m0+row)*2048 + ka) + cb),
        (las_t)((char*)la + (h*1024 + i*512 + wid*64)*16), 16, 0, 0);
  }
  // B: rows h*64 .. h*64+64 (512 slots, 1 per thread)
  {
    int tl = h*512 + t;
    int row = tl >> 3;
    int cb  = ((tl & 7)*16) ^ ((row & 7) << 4);
    __builtin_amdgcn_global_load_lds(
        (gas_t)((const char*)(B + (size_t)(n0+row)*2048 + kb) + cb),
        (las_t)((char*)lb + (h*512 + wid*64)*16), 16, 0, 0);
  }
}

template<int EPI>
__global__ __launch_bounds__(512, 2)
void gemm8(const uint16_t* __restrict__ A, const uint16_t* __restrict__ B,
           float* __restrict__ C,
           uint16_t* __restrict__ qo, uint16_t* __restrict__ ko,
           uint16_t* __restrict__ vo, int N, int nwg)
{
  __shared__ __align__(16) uint16_t lA[3][256*64];   // 96 KB
  __shared__ __align__(16) uint16_t lB[3][128*64];   // 48 KB
  int t = threadIdx.x, lane = t & 63, wid = t >> 6;
  int fq = lane >> 4, fr = lane & 15;

  // XCD-bijective swizzle (nwg % 8 == 0); consecutive wg share the B-panel.
  int cpx = nwg >> 3;
  int orig = blockIdx.x;
  int wg = (orig & 7)*cpx + (orig >> 3);
  int bx = wg & 31, by = wg >> 5;            // M/256 = 32 always
  int m0 = bx*256, n0 = by*128;
  int wm = (wid >> 1)*64, wn = (wid & 1)*64;
  f32x4 acc[4][4] = {};

  // prologue: stage tiles 0 and 1
  stage_half(A, B, lA[0], lB[0], m0, n0, 0, t, wid, 0);
  stage_half(A, B, lA[0], lB[0], m0, n0, 0, t, wid, 1);
  stage_half(A, B, lA[1], lB[1], m0, n0, 1, t, wid, 0);
  stage_half(A, B, lA[1], lB[1], m0, n0, 1, t, wid, 1);

  for (int kt = 0; kt < NKT; ++kt){
    const char* la = (const char*)lA[kt % 3];
    const char* lb = (const char*)lB[kt % 3];
    int pre = kt + 2;
    uint16_t* sa = lA[pre % 3];
    uint16_t* sb = lB[pre % 3];
    bool do_pre = pre < NKT;

#pragma unroll
    for (int ph = 0; ph < 2; ++ph){
      if (ph == 0){
        if (kt < NKT-1) asm volatile("s_waitcnt vmcnt(6)" ::: "memory");
        else            asm volatile("s_waitcnt vmcnt(0)" ::: "memory");
      }
      __builtin_amdgcn_s_barrier();
      __builtin_amdgcn_sched_barrier(0);
      if (do_pre) stage_half(A, B, sa, sb, m0, n0, pre, t, wid, ph);

      short8 af[4], bfr[4];
#pragma unroll
      for (int mi = 0; mi < 4; ++mi){
        int row = wm + mi*16 + fr;
        af[mi] = *(const short8*)(la + row*128 + ((ph*64 + fq*16) ^ ((row&7)<<4)));
      }
#pragma unroll
      for (int ni = 0; ni < 4; ++ni){
        int row = wn + ni*16 + fr;
        bfr[ni] = *(const short8*)(lb + row*128 + ((ph*64 + fq*16) ^ ((row&7)<<4)));
      }
      __builtin_amdgcn_s_setprio(1);
#pragma unroll
      for (int mi = 0; mi < 4; ++mi)
#pragma unroll
        for (int ni = 0; ni < 4; ++ni)
          acc[mi][ni] = __builtin_amdgcn_mfma_f32_16x16x32_bf16(af[mi], bfr[ni],
                                                                acc[mi][ni], 0, 0, 0);
      __builtin_amdgcn_s_setprio(0);
    }
  }

  if (EPI == 0){
#pragma unroll
    for (int mi = 0; mi < 4; ++mi)
#pragma unroll
      for (int ni = 0; ni < 4; ++ni)
#pragma unroll
        for (int r = 0; r < 4; ++r){
          int m = m0 + wm + mi*16 + fq*4 + r;
          int n = n0 + wn + ni*16 + fr;
          C[(size_t)m*N + n] = acc[mi][ni][r];
        }
  } else {
    int cls = n0 >> 10;  // 0=q 1=k 2=v (128-wide tiles never straddle classes)
#pragma unroll
    for (int mi = 0; mi < 4; ++mi)
#pragma unroll
      for (int ni = 0; ni < 4; ++ni)
#pragma unroll
        for (int r = 0; r < 4; ++r){
          int m = m0 + wm + mi*16 + fq*4 + r;
          int n = n0 + wn + ni*16 + fr;
          float v = acc[mi][ni][r];
          int b = m >> 11, s = m & 2047;
          int nn = n & 1023;
          int h = nn >> 6, d = nn & 63;
          int bh = b*NHEAD + h;
          uint16_t hi = f2b(v);
          if (cls == 2){
            vo[((size_t)bh*HDIM + d)*SEQ + s] = hi;          // V transposed [bh][d][s]
          } else {
            uint16_t lo = f2b(v - b2f(hi));
            size_t base = ((size_t)bh*SEQ + s)*128;
            uint16_t* o = (cls == 0) ? qo : ko;
            o[base + d]      = hi;
            o[base + 64 + d] = lo;
          }
        }
  }
}

// ---------------------------------------------------------------------------
// Flash attention (frozen from R3: swapped-operand 32x32, in-reg softmax).
// ---------------------------------------------------------------------------
#define KVB 64
#define NKTILES (SEQ/KVB)   // 32

__device__ __forceinline__ void stage_k(const uint16_t* __restrict__ Kb, int kt,
                                        char* dst, int t, int wid){
  const char* gk = (const char*)(Kb + (size_t)kt*KVB*128);
#pragma unroll
  for (int i = 0; i < 4; ++i){
    int tl = i*256 + t;
    int row = tl >> 4;              // 256B-row index of this thread's 16B slot
    int o   = tl*16;
    __builtin_amdgcn_global_load_lds((gas_t)(gk + (o ^ ((row&7)<<4))),
                                     (las_t)(dst + (i*256 + wid*64)*16),
                                     16, 0, 0);
  }
}

#define MFMA32(A,B,C) __builtin_amdgcn_mfma_f32_32x32x16_bf16(A, B, C, 0, 0, 0)

__global__ __launch_bounds__(256)
void attn_fused(const uint16_t* __restrict__ Qs, const uint16_t* __restrict__ Ks,
                const uint16_t* __restrict__ Vt, float* __restrict__ ctx)
{
  __shared__ __align__(16) char lK[2][KVB*256];   // 2 x 16 KB, swizzled
  int t = threadIdx.x, lane = t & 63, wid = t >> 6;
  int l31 = lane & 31, hi8 = lane >> 5;

  // XCD-bijective swizzle: 1024 blocks = 8 XCD x 128
  int orig = blockIdx.x;
  int wg = (orig & 7) * 128 + (orig >> 3);
  int bh = wg >> 4, qt = wg & 15;

  const uint16_t* Qb = Qs + (size_t)bh*SEQ*128;
  const uint16_t* Kb = Ks + (size_t)bh*SEQ*128;
  const uint16_t* Vb = Vt + (size_t)bh*HDIM*SEQ;
  int qg = qt*128 + wid*32 + l31;        // this lane's q-row

  short8 qfh[4], qfl[4];
#pragma unroll
  for (int c = 0; c < 4; ++c){
    qfh[c] = *(const short8*)&Qb[(size_t)qg*128 + c*16 + hi8*8];
    qfl[c] = *(const short8*)&Qb[(size_t)qg*128 + 64 + c*16 + hi8*8];
  }

  f32x16 av0 = {}, av1 = {};            // ctx accum: d 0-31, 32-63 (cols = q)
  float m = -1e30f, lh = 0.f;           // log2-domain running max; half-local denom

  stage_k(Kb, 0, lK[0], t, wid);
  __syncthreads();
  int cur = 0;

  for (int kt = 0; kt < NKTILES; ++kt){
    if (kt + 1 < NKTILES) stage_k(Kb, kt + 1, lK[cur ^ 1], t, wid);
    const char* kb = lK[cur];
#pragma unroll
    for (int st = 0; st < 2; ++st){
      const uint16_t* vb = Vb + (size_t)l31*SEQ + kt*KVB + st*32 + hi8*8;
      short8 vf00 = *(const short8*)(vb);
      short8 vf01 = *(const short8*)(vb + 16);
      short8 vf10 = *(const short8*)(vb + (size_t)32*SEQ);
      short8 vf11 = *(const short8*)(vb + (size_t)32*SEQ + 16);

      int row = st*32 + l31;
      const char* kr = kb + row*256;
      int rx = (row & 7) << 4;
      f32x16 sc = {};
      __builtin_amdgcn_s_setprio(1);
#pragma unroll
      for (int c = 0; c < 4; ++c){
        short8 kfh = *(const short8*)(kr + ((c*32 + hi8*16) ^ rx));
        short8 kfl = *(const short8*)(kr + ((128 + c*32 + hi8*16) ^ rx));
        sc = MFMA32(kfh, qfh[c], sc);   // qh*kh
        sc = MFMA32(kfh, qfl[c], sc);   // ql*kh
        sc = MFMA32(kfl, qfh[c], sc);   // qh*kl
      }
      __builtin_amdgcn_s_setprio(0);

      // ---- lane-local online softmax (log2 domain) ----
      float x01 = fmaxf(sc[0], sc[1]),   x23 = fmaxf(sc[2], sc[3]);
      float x45 = fmaxf(sc[4], sc[5]),   x67 = fmaxf(sc[6], sc[7]);
      float x89 = fmaxf(sc[8], sc[9]),   xab = fmaxf(sc[10], sc[11]);
      float xcd = fmaxf(sc[12], sc[13]), xef = fmaxf(sc[14], sc[15]);
      float pm = fmaxf(fmaxf(fmaxf(x01, x23), fmaxf(x45, x67)),
                       fmaxf(fmaxf(x89, xab), fmaxf(xcd, xef)));
      pm = fmaxf(pm, __shfl_xor(pm, 32));
      if (__any(pm - m > 8.0f)){        // T13 defer-max
        float mn = fmaxf(m, pm);
        float s = __builtin_amdgcn_exp2f(m - mn);
        lh *= s;
#pragma unroll
        for (int i = 0; i < 16; ++i){ av0[i] *= s; av1[i] *= s; }
        m = mn;
      }
      float p[16];
#pragma unroll
      for (int i = 0; i < 16; ++i) p[i] = __builtin_amdgcn_exp2f(sc[i] - m);
      lh += ((p[0]+p[1])+(p[2]+p[3])) + ((p[4]+p[5])+(p[6]+p[7]))
          + ((p[8]+p[9])+(p[10]+p[11])) + ((p[12]+p[13])+(p[14]+p[15]));

      // ---- P -> A-frag in-register (cvt_pk + permlane32_swap) ----
      uint32_t a0,a1,a2,a3,b0,b1,b2,b3;
      asm("v_cvt_pk_bf16_f32 %0, %1, %2" : "=v"(a0) : "v"(p[0]),  "v"(p[1]));
      asm("v_cvt_pk_bf16_f32 %0, %1, %2" : "=v"(a1) : "v"(p[2]),  "v"(p[3]));
      asm("v_cvt_pk_bf16_f32 %0, %1, %2" : "=v"(a2) : "v"(p[4]),  "v"(p[5]));
      asm("v_cvt_pk_bf16_f32 %0, %1, %2" : "=v"(a3) : "v"(p[6]),  "v"(p[7]));
      asm("v_cvt_pk_bf16_f32 %0, %1, %2" : "=v"(b0) : "v"(p[8]),  "v"(p[9]));
      asm("v_cvt_pk_bf16_f32 %0, %1, %2" : "=v"(b1) : "v"(p[10]), "v"(p[11]));
      asm("v_cvt_pk_bf16_f32 %0, %1, %2" : "=v"(b2) : "v"(p[12]), "v"(p[13]));
      asm("v_cvt_pk_bf16_f32 %0, %1, %2" : "=v"(b3) : "v"(p[14]), "v"(p[15]));
      asm volatile("v_permlane32_swap_b32 %0, %1" : "+v"(a0), "+v"(a2));
      asm volatile("v_permlane32_swap_b32 %0, %1" : "+v"(a1), "+v"(a3));
      asm volatile("v_permlane32_swap_b32 %0, %1" : "+v"(b0), "+v"(b2));
      asm volatile("v_permlane32_swap_b32 %0, %1" : "+v"(b1), "+v"(b3));
      u32x4 w0; w0.x=a0; w0.y=a1; w0.z=a2; w0.w=a3;
      u32x4 w1; w1.x=b0; w1.y=b1; w1.z=b2; w1.w=b3;
      short8 pf0 = __builtin_bit_cast(short8, w0);   // keys 0-15 frag
      short8 pf1 = __builtin_bit_cast(short8, w1);   // keys 16-31 frag

      __builtin_amdgcn_s_setprio(1);
      av0 = MFMA32(vf00, pf0, av0);
      av0 = MFMA32(vf01, pf1, av0);
      av1 = MFMA32(vf10, pf0, av1);
      av1 = MFMA32(vf11, pf1, av1);
      __builtin_amdgcn_s_setprio(0);
    }
    __syncthreads();   // lK[cur] consumers done; staged tile landed
    cur ^= 1;
  }

  float lt = lh + __shfl_xor(lh, 32);
  float linv = 1.0f / lt;
  int b = bh >> 4, h = bh & 15;
  float* orow = ctx + ((size_t)b*SEQ + qg)*HID + h*64;
#pragma unroll
  for (int g = 0; g < 4; ++g){
    f32x4 o0, o1;
#pragma unroll
    for (int i = 0; i < 4; ++i){ o0[i] = av0[g*4+i]*linv; o1[i] = av1[g*4+i]*linv; }
    *(f32x4*)(orow + g*8 + hi8*4)      = o0;   // d = g*8 + hi8*4 + i
    *(f32x4*)(orow + 32 + g*8 + hi8*4) = o1;   // d = 32 + ...
  }
}

// ---------------------------------------------------------------------------
extern "C" void kernel_launch(void* const* d_in, const int* in_sizes, int n_in,
                              void* d_out, int out_size, void* d_ws, size_t ws_size,
                              hipStream_t stream)
{
  const float* x  = (const float*)d_in[0];
  const float* Wq = (const float*)d_in[1];
  const float* Wo = (const float*)d_in[2];
  float* out = (float*)d_out;
  char* ws = (char*)d_ws;

  uint16_t* XS = (uint16_t*)(ws);                 // [8192][2048] x split     33.55 MB
  uint16_t* WQ = (uint16_t*)(ws + 33554432);      // [3072][2048] Wqkv split  12.58 MB
  uint16_t* QS = (uint16_t*)(ws + 46137344);      // [bh][s][128] q hi|lo     33.55 MB
  uint16_t* KS = (uint16_t*)(ws + 79691776);      // [bh][s][128] k hi|lo     33.55 MB
  uint16_t* VT = (uint16_t*)(ws + 113246208);     // [bh][d][s]   v bf16      16.78 MB
  float*    CX = (float*)(ws);                    // ctx fp32 (reuses XS)
  uint16_t* CS = (uint16_t*)(ws + 46137344);      // ctx split (reuses QS)
  uint16_t* WS = (uint16_t*)(ws + 33554432);      // Wout split (reuses WQ)

  // q-scale = att_scale * log2(e)  (exp2-domain softmax)
  const float qs = 0.125f * 1.4426950408889634f;

  split_hilo<<<(MROWS*HID)/256, 256, 0, stream>>>(x, XS, MROWS*HID, 0, 1.0f);
  split_hilo<<<(3*HID*HID)/256, 256, 0, stream>>>(Wq, WQ, 3*HID*HID, HID, qs);

  gemm8<1><<<dim3(768), 512, 0, stream>>>(XS, WQ, nullptr, QS, KS, VT, 3*HID, 768);

  attn_fused<<<dim3(1024), 256, 0, stream>>>(QS, KS, VT, CX);

  split_hilo<<<(MROWS*HID)/256, 256, 0, stream>>>(CX, CS, MROWS*HID, 0, 1.0f);
  split_hilo<<<(HID*HID)/256, 256, 0, stream>>>(Wo, WS, HID*HID, 0, 1.0f);

  gemm8<0><<<dim3(256), 512, 0, stream>>>(CS, WS, out, nullptr, nullptr, nullptr, HID, 256);
}

// Round 5
// 462.908 us; speedup vs baseline: 1.0911x; 1.0911x over previous
//
#include <hip/hip_runtime.h>
#include <hip/hip_bf16.h>
#include <stdint.h>
#include <math.h>

// ---------------------------------------------------------------------------
// SelfAttention: x[4,2048,1024] fp32, W_qkv[3072,1024], W_out[1024,1024]
// bf16 MFMA everywhere; fp32 accuracy via hi/lo split-bf16 GEMMs.
// R5: GEMM = 256x128 tile, 8 waves, k-slice LDS (96 KB, 2dbuf x 2slice),
//     2 fine phases/K-tile {stage || 8 ds_read || 16 MFMA}, counted vmcnt(6)
//     per phase (never 0 in main loop), 2-way-free XOR swizzle, R3's m-fast
//     raster (no XCD remap -- R4's fetch explosion reverted).
//     attn frozen from R3.
// ---------------------------------------------------------------------------

using short8 = __attribute__((ext_vector_type(8))) short;
using f32x4  = __attribute__((ext_vector_type(4))) float;
using f32x16 = __attribute__((ext_vector_type(16))) float;
using u32x4  = __attribute__((ext_vector_type(4))) unsigned int;

#define HID   1024
#define NHEAD 16
#define HDIM  64
#define NB    4
#define SEQ   2048
#define MROWS (NB*SEQ)   // 8192
#define KP    3072       // logical split-K
#define NKT   (KP/64)    // 48 K-tiles of 64

typedef __attribute__((address_space(1))) const void* gas_t;
typedef __attribute__((address_space(3))) void*       las_t;

__device__ __forceinline__ uint16_t f2b(float f){
  uint32_t u = __float_as_uint(f);
  uint32_t r = (u + 0x7FFFu + ((u >> 16) & 1u)) >> 16;   // RNE
  return (uint16_t)r;
}
__device__ __forceinline__ float b2f(uint16_t h){
  return __uint_as_float(((uint32_t)h) << 16);
}

// fp32 [rows][1024] -> bf16 [rows][2048] = [hi | lo]; rows < nscale scaled by qs
__global__ void split_hilo(const float* __restrict__ in, uint16_t* __restrict__ out,
                           int n, int nscale, float qs){
  int i = blockIdx.x * 256 + threadIdx.x;
  if (i >= n) return;
  int r = i >> 10, c = i & 1023;
  float v = in[i];
  if (r < nscale) v *= qs;           // q-scale (incl. log2e for exp2-domain)
  uint16_t hi = f2b(v);
  uint16_t lo = f2b(v - b2f(hi));
  out[(size_t)r*2048 + c]        = hi;
  out[(size_t)r*2048 + 1024 + c] = lo;
}

// ---------------------------------------------------------------------------
// R5 GEMM. C[m][n] = sum_{k'<3072} A2[m][mapA(k')] * B2[n][mapB(k')]
//   mapA = k'<2048 ? k' : k'-2048   (Ah, Al, Ah)
//   mapB = k'<1024 ? k' : k'-1024   (Bh, Bh, Bl)
// LDS: A[2 dbuf][2 kslice][256 rows][32], B[2][2][128][32] bf16 (96 KB).
//   Rows are 64 B (4 x 16B slots); swizzle: slot ^= (row>>1)&3  (2-way free).
//   Staged via global_load_lds, linear dest + inverse-swizzled global source.
// Per K-tile t (dbuf d=t&1), 2 phases (k-slice 0,1):
//   ph0: stage (t+1).k1 -> dbuf d^1 | 8 ds_read (slice 0) | 16 MFMA | vmcnt(6); bar
//   ph1: stage (t+2).k0 -> dbuf d   | 8 ds_read (slice 1) | 16 MFMA | vmcnt(6); bar
// Gate proof: slice needed at next phase was staged 3 phases earlier = 7-9
// loads from newest; vmcnt(6) => all but newest 6 landed. Tail: vmcnt(3)/(0).
// ---------------------------------------------------------------------------
__device__ __forceinline__ void stage_slice(const uint16_t* __restrict__ A,
                                            const uint16_t* __restrict__ B,
                                            uint16_t* la, uint16_t* lb,
                                            int m0, int n0, int kt, int s,
                                            int t, int wid){
  int kp = kt*64;
  int ka = ((kp < 2048) ? kp : kp - 2048) + s*32;
  int kb = ((kp < 1024) ? kp : kp - 1024) + s*32;
#pragma unroll
  for (int i = 0; i < 2; ++i){                    // A slice: 1024 slots, 2/thread
    int slot = i*512 + t;
    int row  = slot >> 2;
    int cc   = (slot & 3) ^ ((row >> 1) & 3);     // inverse swizzle on source
    __builtin_amdgcn_global_load_lds(
        (gas_t)(A + (size_t)(m0+row)*2048 + ka + cc*8),
        (las_t)((char*)la + (i*512 + wid*64)*16), 16, 0, 0);
  }
  {                                               // B slice: 512 slots, 1/thread
    int slot = t;
    int row  = slot >> 2;
    int cc   = (slot & 3) ^ ((row >> 1) & 3);
    __builtin_amdgcn_global_load_lds(
        (gas_t)(B + (size_t)(n0+row)*2048 + kb + cc*8),
        (las_t)((char*)lb + (wid*64)*16), 16, 0, 0);
  }
}

template<int EPI>
__global__ __launch_bounds__(512, 2)
void gemm8(const uint16_t* __restrict__ A, const uint16_t* __restrict__ B,
           float* __restrict__ C,
           uint16_t* __restrict__ qo, uint16_t* __restrict__ ko,
           uint16_t* __restrict__ vo, int N)
{
  __shared__ __align__(16) uint16_t sA[2][2][256*32];   // 64 KB
  __shared__ __align__(16) uint16_t sB[2][2][128*32];   // 32 KB
  int t = threadIdx.x, lane = t & 63, wid = t >> 6;
  int fq = lane >> 4, fr = lane & 15;
  int m0 = blockIdx.x * 256, n0 = blockIdx.y * 128;
  int wm = (wid >> 1) * 64, wn = (wid & 1) * 64;
  f32x4 acc[4][4] = {};

  // prologue: T0 full, T1.k0  (9 loads); vmcnt(3) -> T0's 6 landed
  stage_slice(A, B, &sA[0][0][0], &sB[0][0][0], m0, n0, 0, 0, t, wid);
  stage_slice(A, B, &sA[0][1][0], &sB[0][1][0], m0, n0, 0, 1, t, wid);
  stage_slice(A, B, &sA[1][0][0], &sB[1][0][0], m0, n0, 1, 0, t, wid);
  asm volatile("s_waitcnt vmcnt(3)" ::: "memory");
  __builtin_amdgcn_s_barrier();
  __builtin_amdgcn_sched_barrier(0);

  for (int kt = 0; kt < NKT; ++kt){
    int d = kt & 1;
#pragma unroll
    for (int ph = 0; ph < 2; ++ph){
      // stage (issue first: earliest in flight)
      if (ph == 0){
        if (kt + 1 < NKT)
          stage_slice(A, B, &sA[d^1][1][0], &sB[d^1][1][0], m0, n0, kt+1, 1, t, wid);
      } else {
        if (kt + 2 < NKT)
          stage_slice(A, B, &sA[d][0][0], &sB[d][0][0], m0, n0, kt+2, 0, t, wid);
      }

      const char* la = (const char*)&sA[d][ph][0];
      const char* lb = (const char*)&sB[d][ph][0];
      short8 af[4], bf[4];
#pragma unroll
      for (int mi = 0; mi < 4; ++mi){
        int row = wm + mi*16 + fr;
        af[mi] = *(const short8*)(la + row*64 + ((fq ^ ((row>>1)&3))<<4));
      }
#pragma unroll
      for (int ni = 0; ni < 4; ++ni){
        int row = wn + ni*16 + fr;
        bf[ni] = *(const short8*)(lb + row*64 + ((fq ^ ((row>>1)&3))<<4));
      }
      __builtin_amdgcn_s_setprio(1);
#pragma unroll
      for (int mi = 0; mi < 4; ++mi)
#pragma unroll
        for (int ni = 0; ni < 4; ++ni)
          acc[mi][ni] = __builtin_amdgcn_mfma_f32_16x16x32_bf16(af[mi], bf[ni],
                                                                acc[mi][ni], 0, 0, 0);
      __builtin_amdgcn_s_setprio(0);

      // counted gate + barrier (tail tiles tighten)
      if (ph == 0){
        if (kt < NKT-1) asm volatile("s_waitcnt vmcnt(6)" ::: "memory");
        else            asm volatile("s_waitcnt vmcnt(0)" ::: "memory");
        __builtin_amdgcn_s_barrier();
        __builtin_amdgcn_sched_barrier(0);
      } else if (kt < NKT-1){
        if (kt < NKT-2) asm volatile("s_waitcnt vmcnt(6)" ::: "memory");
        else            asm volatile("s_waitcnt vmcnt(3)" ::: "memory");
        __builtin_amdgcn_s_barrier();
        __builtin_amdgcn_sched_barrier(0);
      }
    }
  }

  if (EPI == 0){
#pragma unroll
    for (int mi = 0; mi < 4; ++mi)
#pragma unroll
      for (int ni = 0; ni < 4; ++ni)
#pragma unroll
        for (int r = 0; r < 4; ++r){
          int m = m0 + wm + mi*16 + fq*4 + r;
          int n = n0 + wn + ni*16 + fr;
          C[(size_t)m*N + n] = acc[mi][ni][r];
        }
  } else {
    int cls = n0 >> 10;  // 0=q 1=k 2=v (128-wide tiles never straddle classes)
#pragma unroll
    for (int mi = 0; mi < 4; ++mi)
#pragma unroll
      for (int ni = 0; ni < 4; ++ni)
#pragma unroll
        for (int r = 0; r < 4; ++r){
          int m = m0 + wm + mi*16 + fq*4 + r;
          int n = n0 + wn + ni*16 + fr;
          float v = acc[mi][ni][r];
          int b = m >> 11, s = m & 2047;
          int nn = n & 1023;
          int h = nn >> 6, d2 = nn & 63;
          int bh = b*NHEAD + h;
          uint16_t hi = f2b(v);
          if (cls == 2){
            vo[((size_t)bh*HDIM + d2)*SEQ + s] = hi;         // V transposed [bh][d][s]
          } else {
            uint16_t lo = f2b(v - b2f(hi));
            size_t base = ((size_t)bh*SEQ + s)*128;
            uint16_t* o = (cls == 0) ? qo : ko;
            o[base + d2]      = hi;
            o[base + 64 + d2] = lo;
          }
        }
  }
}

// ---------------------------------------------------------------------------
// Flash attention (frozen from R3: swapped-operand 32x32, in-reg softmax).
// ---------------------------------------------------------------------------
#define KVB 64
#define NKTILES (SEQ/KVB)   // 32

__device__ __forceinline__ void stage_k(const uint16_t* __restrict__ Kb, int kt,
                                        char* dst, int t, int wid){
  const char* gk = (const char*)(Kb + (size_t)kt*KVB*128);
#pragma unroll
  for (int i = 0; i < 4; ++i){
    int tl = i*256 + t;
    int row = tl >> 4;              // 256B-row index of this thread's 16B slot
    int o   = tl*16;
    __builtin_amdgcn_global_load_lds((gas_t)(gk + (o ^ ((row&7)<<4))),
                                     (las_t)(dst + (i*256 + wid*64)*16),
                                     16, 0, 0);
  }
}

#define MFMA32(A,B,C) __builtin_amdgcn_mfma_f32_32x32x16_bf16(A, B, C, 0, 0, 0)

__global__ __launch_bounds__(256)
void attn_fused(const uint16_t* __restrict__ Qs, const uint16_t* __restrict__ Ks,
                const uint16_t* __restrict__ Vt, float* __restrict__ ctx)
{
  __shared__ __align__(16) char lK[2][KVB*256];   // 2 x 16 KB, swizzled
  int t = threadIdx.x, lane = t & 63, wid = t >> 6;
  int l31 = lane & 31, hi8 = lane >> 5;

  // XCD-bijective swizzle: 1024 blocks = 8 XCD x 128
  int orig = blockIdx.x;
  int wg = (orig & 7) * 128 + (orig >> 3);
  int bh = wg >> 4, qt = wg & 15;

  const uint16_t* Qb = Qs + (size_t)bh*SEQ*128;
  const uint16_t* Kb = Ks + (size_t)bh*SEQ*128;
  const uint16_t* Vb = Vt + (size_t)bh*HDIM*SEQ;
  int qg = qt*128 + wid*32 + l31;        // this lane's q-row

  short8 qfh[4], qfl[4];
#pragma unroll
  for (int c = 0; c < 4; ++c){
    qfh[c] = *(const short8*)&Qb[(size_t)qg*128 + c*16 + hi8*8];
    qfl[c] = *(const short8*)&Qb[(size_t)qg*128 + 64 + c*16 + hi8*8];
  }

  f32x16 av0 = {}, av1 = {};            // ctx accum: d 0-31, 32-63 (cols = q)
  float m = -1e30f, lh = 0.f;           // log2-domain running max; half-local denom

  stage_k(Kb, 0, lK[0], t, wid);
  __syncthreads();
  int cur = 0;

  for (int kt = 0; kt < NKTILES; ++kt){
    if (kt + 1 < NKTILES) stage_k(Kb, kt + 1, lK[cur ^ 1], t, wid);
    const char* kb = lK[cur];
#pragma unroll
    for (int st = 0; st < 2; ++st){
      const uint16_t* vb = Vb + (size_t)l31*SEQ + kt*KVB + st*32 + hi8*8;
      short8 vf00 = *(const short8*)(vb);
      short8 vf01 = *(const short8*)(vb + 16);
      short8 vf10 = *(const short8*)(vb + (size_t)32*SEQ);
      short8 vf11 = *(const short8*)(vb + (size_t)32*SEQ + 16);

      int row = st*32 + l31;
      const char* kr = kb + row*256;
      int rx = (row & 7) << 4;
      f32x16 sc = {};
      __builtin_amdgcn_s_setprio(1);
#pragma unroll
      for (int c = 0; c < 4; ++c){
        short8 kfh = *(const short8*)(kr + ((c*32 + hi8*16) ^ rx));
        short8 kfl = *(const short8*)(kr + ((128 + c*32 + hi8*16) ^ rx));
        sc = MFMA32(kfh, qfh[c], sc);   // qh*kh
        sc = MFMA32(kfh, qfl[c], sc);   // ql*kh
        sc = MFMA32(kfl, qfh[c], sc);   // qh*kl
      }
      __builtin_amdgcn_s_setprio(0);

      // ---- lane-local online softmax (log2 domain) ----
      float x01 = fmaxf(sc[0], sc[1]),   x23 = fmaxf(sc[2], sc[3]);
      float x45 = fmaxf(sc[4], sc[5]),   x67 = fmaxf(sc[6], sc[7]);
      float x89 = fmaxf(sc[8], sc[9]),   xab = fmaxf(sc[10], sc[11]);
      float xcd = fmaxf(sc[12], sc[13]), xef = fmaxf(sc[14], sc[15]);
      float pm = fmaxf(fmaxf(fmaxf(x01, x23), fmaxf(x45, x67)),
                       fmaxf(fmaxf(x89, xab), fmaxf(xcd, xef)));
      pm = fmaxf(pm, __shfl_xor(pm, 32));
      if (__any(pm - m > 8.0f)){        // T13 defer-max
        float mn = fmaxf(m, pm);
        float s = __builtin_amdgcn_exp2f(m - mn);
        lh *= s;
#pragma unroll
        for (int i = 0; i < 16; ++i){ av0[i] *= s; av1[i] *= s; }
        m = mn;
      }
      float p[16];
#pragma unroll
      for (int i = 0; i < 16; ++i) p[i] = __builtin_amdgcn_exp2f(sc[i] - m);
      lh += ((p[0]+p[1])+(p[2]+p[3])) + ((p[4]+p[5])+(p[6]+p[7]))
          + ((p[8]+p[9])+(p[10]+p[11])) + ((p[12]+p[13])+(p[14]+p[15]));

      // ---- P -> A-frag in-register (cvt_pk + permlane32_swap) ----
      uint32_t a0,a1,a2,a3,b0,b1,b2,b3;
      asm("v_cvt_pk_bf16_f32 %0, %1, %2" : "=v"(a0) : "v"(p[0]),  "v"(p[1]));
      asm("v_cvt_pk_bf16_f32 %0, %1, %2" : "=v"(a1) : "v"(p[2]),  "v"(p[3]));
      asm("v_cvt_pk_bf16_f32 %0, %1, %2" : "=v"(a2) : "v"(p[4]),  "v"(p[5]));
      asm("v_cvt_pk_bf16_f32 %0, %1, %2" : "=v"(a3) : "v"(p[6]),  "v"(p[7]));
      asm("v_cvt_pk_bf16_f32 %0, %1, %2" : "=v"(b0) : "v"(p[8]),  "v"(p[9]));
      asm("v_cvt_pk_bf16_f32 %0, %1, %2" : "=v"(b1) : "v"(p[10]), "v"(p[11]));
      asm("v_cvt_pk_bf16_f32 %0, %1, %2" : "=v"(b2) : "v"(p[12]), "v"(p[13]));
      asm("v_cvt_pk_bf16_f32 %0, %1, %2" : "=v"(b3) : "v"(p[14]), "v"(p[15]));
      asm volatile("v_permlane32_swap_b32 %0, %1" : "+v"(a0), "+v"(a2));
      asm volatile("v_permlane32_swap_b32 %0, %1" : "+v"(a1), "+v"(a3));
      asm volatile("v_permlane32_swap_b32 %0, %1" : "+v"(b0), "+v"(b2));
      asm volatile("v_permlane32_swap_b32 %0, %1" : "+v"(b1), "+v"(b3));
      u32x4 w0; w0.x=a0; w0.y=a1; w0.z=a2; w0.w=a3;
      u32x4 w1; w1.x=b0; w1.y=b1; w1.z=b2; w1.w=b3;
      short8 pf0 = __builtin_bit_cast(short8, w0);   // keys 0-15 frag
      short8 pf1 = __builtin_bit_cast(short8, w1);   // keys 16-31 frag

      __builtin_amdgcn_s_setprio(1);
      av0 = MFMA32(vf00, pf0, av0);
      av0 = MFMA32(vf01, pf1, av0);
      av1 = MFMA32(vf10, pf0, av1);
      av1 = MFMA32(vf11, pf1, av1);
      __builtin_amdgcn_s_setprio(0);
    }
    __syncthreads();   // lK[cur] consumers done; staged tile landed
    cur ^= 1;
  }

  float lt = lh + __shfl_xor(lh, 32);
  float linv = 1.0f / lt;
  int b = bh >> 4, h = bh & 15;
  float* orow = ctx + ((size_t)b*SEQ + qg)*HID + h*64;
#pragma unroll
  for (int g = 0; g < 4; ++g){
    f32x4 o0, o1;
#pragma unroll
    for (int i = 0; i < 4; ++i){ o0[i] = av0[g*4+i]*linv; o1[i] = av1[g*4+i]*linv; }
    *(f32x4*)(orow + g*8 + hi8*4)      = o0;   // d = g*8 + hi8*4 + i
    *(f32x4*)(orow + 32 + g*8 + hi8*4) = o1;   // d = 32 + ...
  }
}

// ---------------------------------------------------------------------------
extern "C" void kernel_launch(void* const* d_in, const int* in_sizes, int n_in,
                              void* d_out, int out_size, void* d_ws, size_t ws_size,
                              hipStream_t stream)
{
  const float* x  = (const float*)d_in[0];
  const float* Wq = (const float*)d_in[1];
  const float* Wo = (const float*)d_in[2];
  float* out = (float*)d_out;
  char* ws = (char*)d_ws;

  uint16_t* XS = (uint16_t*)(ws);                 // [8192][2048] x split     33.55 MB
  uint16_t* WQ = (uint16_t*)(ws + 33554432);      // [3072][2048] Wqkv split  12.58 MB
  uint16_t* QS = (uint16_t*)(ws + 46137344);      // [bh][s][128] q hi|lo     33.55 MB
  uint16_t* KS = (uint16_t*)(ws + 79691776);      // [bh][s][128] k hi|lo     33.55 MB
  uint16_t* VT = (uint16_t*)(ws + 113246208);     // [bh][d][s]   v bf16      16.78 MB
  float*    CX = (float*)(ws);                    // ctx fp32 (reuses XS)
  uint16_t* CS = (uint16_t*)(ws + 46137344);      // ctx split (reuses QS)
  uint16_t* WS = (uint16_t*)(ws + 33554432);      // Wout split (reuses WQ)

  // q-scale = att_scale * log2(e)  (exp2-domain softmax)
  const float qs = 0.125f * 1.4426950408889634f;

  split_hilo<<<(MROWS*HID)/256, 256, 0, stream>>>(x, XS, MROWS*HID, 0, 1.0f);
  split_hilo<<<(3*HID*HID)/256, 256, 0, stream>>>(Wq, WQ, 3*HID*HID, HID, qs);

  gemm8<1><<<dim3(32, 24), 512, 0, stream>>>(XS, WQ, nullptr, QS, KS, VT, 3*HID);

  attn_fused<<<dim3(1024), 256, 0, stream>>>(QS, KS, VT, CX);

  split_hilo<<<(MROWS*HID)/256, 256, 0, stream>>>(CX, CS, MROWS*HID, 0, 1.0f);
  split_hilo<<<(HID*HID)/256, 256, 0, stream>>>(Wo, WS, HID*HID, 0, 1.0f);

  gemm8<0><<<dim3(32, 8), 512, 0, stream>>>(CS, WS, out, nullptr, nullptr, nullptr, HID);
}